// Round 16
// baseline (1903.596 us; speedup 1.0000x reference)
//
#include <hip/hip_runtime.h>
#include <hip/hip_fp8.h>
#include <stdint.h>
#include <math.h>

typedef unsigned short u16;
typedef __attribute__((ext_vector_type(4))) short s16x4;
typedef __attribute__((ext_vector_type(4))) float f32x4;
typedef __attribute__((ext_vector_type(2))) long long llx2;

typedef __attribute__((address_space(1))) const uint32_t gas_u32;
typedef __attribute__((address_space(3))) uint32_t las_u32;

__device__ __forceinline__ u16 f2b(float f) {
  union { float f; uint32_t u; } v; v.f = f;
  uint32_t r = v.u + 0x7FFFu + ((v.u >> 16) & 1u);
  return (u16)(r >> 16);
}
__device__ __forceinline__ float b2f(u16 b) {
  union { uint32_t u; float f; } v; v.u = ((uint32_t)b) << 16; return v.f;
}
__device__ __forceinline__ uint8_t f8(float x) {
  __hip_fp8_e4m3 t(x);
  return (uint8_t)t.__x;
}
// k-interleaved fp8 position (I64)
__device__ __forceinline__ int ipos(int k) {
  return (k & ~63) | (k & 7) | ((k & 32) >> 2) | ((k & 24) << 1);
}

__device__ __forceinline__ void gl_lds16(const void* g, void* l) {
  __builtin_amdgcn_global_load_lds((gas_u32*)g, (las_u32*)l, 16, 0, 0);
}
__device__ __forceinline__ void barrier_raw() {
  asm volatile("" ::: "memory");
  __builtin_amdgcn_s_barrier();
  asm volatile("" ::: "memory");
}

#define MM8(A_, B_, C_) __builtin_amdgcn_mfma_f32_16x16x32_fp8_fp8(A_, B_, C_, 0, 0, 0)

__device__ __forceinline__ void xcd_swz(int nwg, int orig, int gx, int& bx, int& by) {
  const int xcd = orig & 7, rem = orig >> 3;
  const int qq = nwg >> 3, rr = nwg & 7;
  const int wg = (xcd < rr ? xcd * (qq + 1) : rr * (qq + 1) + (xcd - rr) * qq) + rem;
  bx = wg % gx; by = wg / gx;
}

struct GP8 {
  const uint8_t* A; long long asb;
  const uint8_t* B[3]; long long bsb;
  uint8_t* O[3]; long long osb;
  int K, lda, ldb, ldo;
  float m1[3], m2[3];
  int epi[3];            // 0 fp8 | 1 fp8 transposed | 2 quad fp8 | 3 residual | 4 f32-NT
  int nsel, msel;
  float qc;
  u16* xres; const float* lnw; float rscale; float oscale;
  uint8_t* h8out;
  float* fout; int ldf;
};

// shared fp8 epilogue body (per-fragment)
#define EPI_FRAG() do { \
  if (epi == 0) { \
    _Pragma("unroll") \
    for (int r = 0; r < 4; ++r) { \
      float y = (v[r] * m1v) * m2v; \
      Op[(size_t)(rbase + r) * p.ldo + ipos(col)] = f8(y); \
    } \
  } else if (epi == 1) { \
    const int b = rbase >> 11, rb = rbase & 2047; \
    uint32_t pk = 0; \
    _Pragma("unroll") \
    for (int r = 0; r < 4; ++r) { \
      float y = (v[r] * m1v) * m2v; \
      pk |= (uint32_t)f8(y) << (8 * r); \
    } \
    *(uint32_t*)(Op + (size_t)b * 2097152 + (size_t)col * 2048 + ipos(rb)) = pk; \
  } else if (epi == 2) { \
    _Pragma("unroll") \
    for (int r = 0; r < 4; ++r) { \
      float u = (v[r] * m1v) * m2v; \
      Op[(size_t)(rbase + r) * p.ldo + ipos(col)] = f8(u * u * p.qc + u); \
    } \
  } else if (epi == 3) { \
    _Pragma("unroll") \
    for (int r = 0; r < 4; ++r) { \
      float add = (v[r] * m1v) * m2v; \
      size_t ix = (size_t)(rbase + r) * 1024 + col; \
      float xn = (b2f(p.xres[ix]) + add) * p.rscale; \
      p.xres[ix] = f2b(xn); \
      float hv = xn * p.lnw[col] * 0.1f; \
      p.h8out[(size_t)(rbase + r) * 1024 + ipos(col)] = f8(hv * p.oscale); \
    } \
  } else { \
    _Pragma("unroll") \
    for (int r = 0; r < 4; ++r) \
      __builtin_nontemporal_store((v[r] * m1v) * m2v, \
                                  &p.fout[(size_t)(rbase + r) * p.ldf + col]); \
  } \
} while (0)

// ------------------------------------------------------------- gemm8p (fp8) --
// 256x128 tile, BK=64, 4 waves (2M x 2N), wave 128x64 with B-reg-reuse:
// 187 B LDS/MFMA (~83% cap). Triple-buffered 72KB, 1 phase/tile
// (64 MFMA/barrier), counted vmcnt(6). lm_head + QKU.
#define P8SA(b, t) do { \
  gl_lds16(gA0 + (size_t)(t) * 64,              lds + (b) * 24576 + wid * 1024); \
  gl_lds16(gA0 + (size_t)(t) * 64 + arow64,     lds + (b) * 24576 + 4096 + wid * 1024); \
  gl_lds16(gA0 + (size_t)(t) * 64 + 2 * arow64, lds + (b) * 24576 + 8192 + wid * 1024); \
  gl_lds16(gA0 + (size_t)(t) * 64 + 3 * arow64, lds + (b) * 24576 + 12288 + wid * 1024); \
} while (0)
#define P8SB(b, t) do { \
  gl_lds16(gB0 + (size_t)(t) * 64,          lds + (b) * 24576 + 16384 + wid * 1024); \
  gl_lds16(gB0 + (size_t)(t) * 64 + brow64, lds + (b) * 24576 + 20480 + wid * 1024); \
} while (0)

__global__ __launch_bounds__(256, 2) void gemm8p_k(GP8 p) {
  extern __shared__ __attribute__((aligned(16))) char lds[];
  const int z = blockIdx.z;
  int bx, by;
  xcd_swz(gridDim.x * gridDim.y, blockIdx.y * gridDim.x + blockIdx.x, gridDim.x, bx, by);
  const int n0 = bx * 128, m0 = by * 256;          // n-fastest
  const int zi = p.nsel ? (n0 >> 10) : 0;
  const int nB = p.nsel ? (n0 & 1023) : n0;
  const uint8_t* __restrict__ Ap = p.A + (size_t)z * p.asb;
  const uint8_t* __restrict__ Bp = p.B[zi] + (size_t)(p.msel ? (m0 >> 11) : z) * p.bsb;

  const int tid = threadIdx.x, wid = tid >> 6, lane = tid & 63;
  const int wm = wid >> 1, wn = wid & 1;
  const int l15 = lane & 15, l4 = lane >> 4;
  const int cswz16 = (l4 ^ ((l15 >> 1) & 3)) * 16;

  const f32x4 vzero = {0.f, 0.f, 0.f, 0.f};
  f32x4 acc[8][4];
#pragma unroll
  for (int i = 0; i < 8; ++i)
#pragma unroll
    for (int j = 0; j < 4; ++j) acc[i][j] = vzero;

  const int sr = lane >> 2;
  const int cgB = ((lane & 3) ^ ((lane >> 3) & 3)) * 16;
  const uint8_t* gA0 = Ap + (size_t)(m0 + wid * 16 + sr) * p.lda + cgB;
  const uint8_t* gB0 = Bp + (size_t)(nB + wid * 16 + sr) * p.ldb + cgB;
  const size_t arow64 = (size_t)64 * p.lda;
  const size_t brow64 = (size_t)64 * p.ldb;

  const int nt = p.K >> 6;   // BK=64 fp8 (>= 2 always)

  P8SA(0, 0); P8SB(0, 0);
  P8SA(1, 1); P8SB(1, 1);
  asm volatile("s_waitcnt vmcnt(6)" ::: "memory");
  barrier_raw();

  int q = 0;
  for (int t = 0; t < nt; ++t) {
    const int bn = (q == 0) ? 2 : q - 1;           // (q+2)%3
    const char* Abase = lds + q * 24576 + (wm * 128 + l15) * 64 + cswz16;
    const char* Bbase = lds + q * 24576 + 16384 + (wn * 64 + l15) * 64 + cswz16;
    llx2 av[8], bv[4];
#pragma unroll
    for (int mi = 0; mi < 8; ++mi) av[mi] = *(const llx2*)(Abase + mi * 1024);
#pragma unroll
    for (int ni = 0; ni < 4; ++ni) bv[ni] = *(const llx2*)(Bbase + ni * 1024);
    if (t + 2 < nt) { P8SA(bn, t + 2); P8SB(bn, t + 2); }
    asm volatile("s_waitcnt lgkmcnt(0)" ::: "memory");
    __builtin_amdgcn_sched_barrier(0);
    __builtin_amdgcn_s_setprio(1);
#pragma unroll
    for (int mi = 0; mi < 8; ++mi)
#pragma unroll
      for (int ni = 0; ni < 4; ++ni) {
        acc[mi][ni] = MM8(av[mi][0], bv[ni][0], acc[mi][ni]);
        acc[mi][ni] = MM8(av[mi][1], bv[ni][1], acc[mi][ni]);
      }
    __builtin_amdgcn_s_setprio(0);
    __builtin_amdgcn_sched_barrier(0);
    if (t + 2 < nt) asm volatile("s_waitcnt vmcnt(6)" ::: "memory");
    else            asm volatile("s_waitcnt vmcnt(0)" ::: "memory");
    barrier_raw();
    q = (q == 2) ? 0 : q + 1;
  }

  const int epi = p.epi[zi];
  const float m1v = p.m1[zi], m2v = p.m2[zi];
  uint8_t* __restrict__ Op = p.O[zi] + (size_t)z * p.osb;
#pragma unroll
  for (int mi = 0; mi < 8; ++mi) {
    const int rbase = m0 + wm * 128 + mi * 16 + l4 * 4;
#pragma unroll
    for (int ni = 0; ni < 4; ++ni) {
      const int col = nB + wn * 64 + ni * 16 + l15;
      f32x4 v = acc[mi][ni];
      EPI_FRAG();
    }
  }
}

// ------------------------------------------------------------- gemm8t (fp8) --
// 128x128 tile, BK=64, 4 waves (2x2) 64x64, TRIPLE-buffered 48KB -> 3 blk/CU,
// 1 phase/tile (32 MFMA/barrier), counted vmcnt(4). qk/fc1/Wvo.
#define T8SA(b, t) do { \
  gl_lds16(gA0 + (size_t)(t) * 64,          lds + (b) * 16384 + wid * 1024); \
  gl_lds16(gA0 + (size_t)(t) * 64 + arow64, lds + (b) * 16384 + 4096 + wid * 1024); \
} while (0)
#define T8SB(b, t) do { \
  gl_lds16(gB0 + (size_t)(t) * 64,          lds + (b) * 16384 + 8192 + wid * 1024); \
  gl_lds16(gB0 + (size_t)(t) * 64 + brow64, lds + (b) * 16384 + 12288 + wid * 1024); \
} while (0)

__global__ __launch_bounds__(256, 3) void gemm8t_k(GP8 p) {
  extern __shared__ __attribute__((aligned(16))) char lds[];
  const int z = blockIdx.z;
  int bx, by;
  xcd_swz(gridDim.x * gridDim.y, blockIdx.y * gridDim.x + blockIdx.x, gridDim.x, bx, by);
  const int m0 = bx * 128, n0 = by * 128;          // m-fastest
  const int zi = p.nsel ? (n0 >> 10) : 0;
  const int nB = p.nsel ? (n0 & 1023) : n0;
  const uint8_t* __restrict__ Ap = p.A + (size_t)z * p.asb;
  const uint8_t* __restrict__ Bp = p.B[zi] + (size_t)(p.msel ? (m0 >> 11) : z) * p.bsb;

  const int tid = threadIdx.x, wid = tid >> 6, lane = tid & 63;
  const int wm = wid >> 1, wn = wid & 1;
  const int l15 = lane & 15, l4 = lane >> 4;
  const int cswz16 = (l4 ^ ((l15 >> 1) & 3)) * 16;

  const f32x4 vzero = {0.f, 0.f, 0.f, 0.f};
  f32x4 acc[4][4];
#pragma unroll
  for (int i = 0; i < 4; ++i)
#pragma unroll
    for (int j = 0; j < 4; ++j) acc[i][j] = vzero;

  const int sr = lane >> 2;
  const int cgB = ((lane & 3) ^ ((lane >> 3) & 3)) * 16;
  const uint8_t* gA0 = Ap + (size_t)(m0 + wid * 16 + sr) * p.lda + cgB;
  const uint8_t* gB0 = Bp + (size_t)(nB + wid * 16 + sr) * p.ldb + cgB;
  const size_t arow64 = (size_t)64 * p.lda;
  const size_t brow64 = (size_t)64 * p.ldb;

  const int nt = p.K >> 6;   // >= 16 for all uses

  T8SA(0, 0); T8SB(0, 0);
  T8SA(1, 1); T8SB(1, 1);
  asm volatile("s_waitcnt vmcnt(4)" ::: "memory");
  barrier_raw();

  int q = 0;
  for (int t = 0; t < nt; ++t) {
    const int bn = (q == 0) ? 2 : q - 1;           // (q+2)%3
    const char* Abase = lds + q * 16384 + (wm * 64 + l15) * 64 + cswz16;
    const char* Bbase = lds + q * 16384 + 8192 + (wn * 64 + l15) * 64 + cswz16;
    llx2 av[4], bv[4];
#pragma unroll
    for (int mi = 0; mi < 4; ++mi) av[mi] = *(const llx2*)(Abase + mi * 1024);
#pragma unroll
    for (int ni = 0; ni < 4; ++ni) bv[ni] = *(const llx2*)(Bbase + ni * 1024);
    if (t + 2 < nt) { T8SA(bn, t + 2); T8SB(bn, t + 2); }
    asm volatile("s_waitcnt lgkmcnt(0)" ::: "memory");
    __builtin_amdgcn_sched_barrier(0);
    __builtin_amdgcn_s_setprio(1);
#pragma unroll
    for (int mi = 0; mi < 4; ++mi)
#pragma unroll
      for (int ni = 0; ni < 4; ++ni) {
        acc[mi][ni] = MM8(av[mi][0], bv[ni][0], acc[mi][ni]);
        acc[mi][ni] = MM8(av[mi][1], bv[ni][1], acc[mi][ni]);
      }
    __builtin_amdgcn_s_setprio(0);
    __builtin_amdgcn_sched_barrier(0);
    if (t + 2 < nt) asm volatile("s_waitcnt vmcnt(4)" ::: "memory");
    else            asm volatile("s_waitcnt vmcnt(0)" ::: "memory");
    barrier_raw();
    q = (q == 2) ? 0 : q + 1;
  }

  const int epi = p.epi[zi];
  const float m1v = p.m1[zi], m2v = p.m2[zi];
  uint8_t* __restrict__ Op = p.O[zi] + (size_t)z * p.osb;
#pragma unroll
  for (int mi = 0; mi < 4; ++mi) {
    const int rbase = m0 + wm * 64 + mi * 16 + l4 * 4;
#pragma unroll
    for (int ni = 0; ni < 4; ++ni) {
      const int col = nB + wn * 64 + ni * 16 + l15;
      f32x4 v = acc[mi][ni];
      EPI_FRAG();
    }
  }
}

// ------------------------------------------------------------- gemm8h (fp8) --
// 64x128 tile, 4 waves of 32x64, BK=128, triple-buffer 72KB, 1 phase/tile.
// au/fc2 (N=1024 ops, dense 512-block grids).
#define H8STAGE(b, t) do { \
  gl_lds16(gA0 + (size_t)(t) * 128,      lds + (b) * 24576 + wid * 1024); \
  gl_lds16(gB0 + (size_t)(t) * 128,      lds + (b) * 24576 + 8192 + wid * 1024); \
  gl_lds16(gB1 + (size_t)(t) * 128,      lds + (b) * 24576 + 12288 + wid * 1024); \
  gl_lds16(gA0 + (size_t)(t) * 128 + 64, lds + (b) * 24576 + 4096 + wid * 1024); \
  gl_lds16(gB0 + (size_t)(t) * 128 + 64, lds + (b) * 24576 + 16384 + wid * 1024); \
  gl_lds16(gB1 + (size_t)(t) * 128 + 64, lds + (b) * 24576 + 20480 + wid * 1024); \
} while (0)

#define MF8H(AK, BK_) do { \
  acc[0][0]=MM8(a0##AK[0],b0##BK_[0],acc[0][0]); acc[0][0]=MM8(a0##AK[1],b0##BK_[1],acc[0][0]); \
  acc[0][1]=MM8(a0##AK[0],b1##BK_[0],acc[0][1]); acc[0][1]=MM8(a0##AK[1],b1##BK_[1],acc[0][1]); \
  acc[0][2]=MM8(a0##AK[0],b2##BK_[0],acc[0][2]); acc[0][2]=MM8(a0##AK[1],b2##BK_[1],acc[0][2]); \
  acc[0][3]=MM8(a0##AK[0],b3##BK_[0],acc[0][3]); acc[0][3]=MM8(a0##AK[1],b3##BK_[1],acc[0][3]); \
  acc[1][0]=MM8(a1##AK[0],b0##BK_[0],acc[1][0]); acc[1][0]=MM8(a1##AK[1],b0##BK_[1],acc[1][0]); \
  acc[1][1]=MM8(a1##AK[0],b1##BK_[0],acc[1][1]); acc[1][1]=MM8(a1##AK[1],b1##BK_[1],acc[1][1]); \
  acc[1][2]=MM8(a1##AK[0],b2##BK_[0],acc[1][2]); acc[1][2]=MM8(a1##AK[1],b2##BK_[1],acc[1][2]); \
  acc[1][3]=MM8(a1##AK[0],b3##BK_[0],acc[1][3]); acc[1][3]=MM8(a1##AK[1],b3##BK_[1],acc[1][3]); \
} while (0)

__global__ __launch_bounds__(256, 2) void gemm8h_k(GP8 p) {
  extern __shared__ __attribute__((aligned(16))) char lds[];
  const int z = blockIdx.z;
  int bx, by;
  xcd_swz(gridDim.x * gridDim.y, blockIdx.y * gridDim.x + blockIdx.x, gridDim.x, bx, by);
  const int m0 = bx * 64, n0 = by * 128;
  const int zi = p.nsel ? (n0 >> 10) : 0;
  const int nB = p.nsel ? (n0 & 1023) : n0;
  const uint8_t* __restrict__ Ap = p.A + (size_t)z * p.asb;
  const uint8_t* __restrict__ Bp = p.B[zi] + (size_t)(p.msel ? (m0 >> 11) : z) * p.bsb;

  const int tid = threadIdx.x, wid = tid >> 6, lane = tid & 63;
  const int wm = wid >> 1, wn = wid & 1;
  const int l15 = lane & 15, l4 = lane >> 4;
  const int cswz16 = (l4 ^ ((l15 >> 1) & 3)) * 16;

  const f32x4 vzero = {0.f, 0.f, 0.f, 0.f};
  f32x4 acc[2][4];
#pragma unroll
  for (int i = 0; i < 2; ++i)
#pragma unroll
    for (int j = 0; j < 4; ++j) acc[i][j] = vzero;

  const int sr = lane >> 2;
  const int cgB = ((lane & 3) ^ ((lane >> 3) & 3)) * 16;
  const uint8_t* gA0 = Ap + (size_t)(m0 + wid * 16 + sr) * p.lda + cgB;
  const uint8_t* gB0 = Bp + (size_t)(nB + wid * 16 + sr) * p.ldb + cgB;
  const uint8_t* gB1 = gB0 + (size_t)64 * p.ldb;

  const int nt = p.K >> 7;

  H8STAGE(0, 0);
  H8STAGE(1, 1);
  asm volatile("s_waitcnt vmcnt(6)" ::: "memory");
  barrier_raw();

  int q = 0;
  for (int t = 0; t < nt; ++t) {
    const int bn = (q == 0) ? 2 : q - 1;
    const char* Abase = lds + q * 24576 + (wm * 32 + l15) * 64 + cswz16;
    const char* Bbase = lds + q * 24576 + 8192 + (wn * 64 + l15) * 64 + cswz16;
    llx2 a0k0 = *(const llx2*)Abase;
    llx2 a1k0 = *(const llx2*)(Abase + 1024);
    llx2 a0k1 = *(const llx2*)(Abase + 4096);
    llx2 a1k1 = *(const llx2*)(Abase + 4096 + 1024);
    llx2 b0k0 = *(const llx2*)Bbase;
    llx2 b1k0 = *(const llx2*)(Bbase + 1024);
    llx2 b2k0 = *(const llx2*)(Bbase + 2048);
    llx2 b3k0 = *(const llx2*)(Bbase + 3072);
    llx2 b0k1 = *(const llx2*)(Bbase + 8192);
    llx2 b1k1 = *(const llx2*)(Bbase + 8192 + 1024);
    llx2 b2k1 = *(const llx2*)(Bbase + 8192 + 2048);
    llx2 b3k1 = *(const llx2*)(Bbase + 8192 + 3072);
    if (t + 2 < nt) H8STAGE(bn, t + 2);
    asm volatile("s_waitcnt lgkmcnt(0)" ::: "memory");
    __builtin_amdgcn_sched_barrier(0);
    __builtin_amdgcn_s_setprio(1);
    MF8H(k0, k0);
    MF8H(k1, k1);
    __builtin_amdgcn_s_setprio(0);
    __builtin_amdgcn_sched_barrier(0);
    if (t + 2 < nt) asm volatile("s_waitcnt vmcnt(6)" ::: "memory");
    else            asm volatile("s_waitcnt vmcnt(0)" ::: "memory");
    barrier_raw();
    q = (q == 2) ? 0 : q + 1;
  }

  const int epi = p.epi[zi];
  const float m1v = p.m1[zi], m2v = p.m2[zi];
  uint8_t* __restrict__ Op = p.O[zi] + (size_t)z * p.osb;
#pragma unroll
  for (int mi = 0; mi < 2; ++mi) {
    const int rbase = m0 + wm * 32 + mi * 16 + l4 * 4;
#pragma unroll
    for (int ni = 0; ni < 4; ++ni) {
      const int col = nB + wn * 64 + ni * 16 + l15;
      f32x4 v = acc[mi][ni];
      EPI_FRAG();
    }
  }
}

// ----------------------------------------------------------------- helpers --
__global__ __launch_bounds__(256) void embed8_k(const int* __restrict__ idx, const float* __restrict__ wte,
                                                const float* __restrict__ wpe, const float* __restrict__ ln1,
                                                u16* __restrict__ x, uint8_t* __restrict__ h8, float sh) {
  const int bt = blockIdx.x;
  const int t = bt & 2047;
  const int tok = idx[bt];
  const int e = threadIdx.x * 4;
  const float4 wv = *(const float4*)(wte + (size_t)tok * 1024 + e);
  const float4 pv = *(const float4*)(wpe + (size_t)t * 1024 + e);
  const float4 lv = *(const float4*)(ln1 + e);
  float4 xo;
  xo.x = (wv.x + pv.x) * 0.01f;
  xo.y = (wv.y + pv.y) * 0.01f;
  xo.z = (wv.z + pv.z) * 0.01f;
  xo.w = (wv.w + pv.w) * 0.01f;
  s16x4 xb;
  xb[0] = (short)f2b(xo.x); xb[1] = (short)f2b(xo.y);
  xb[2] = (short)f2b(xo.z); xb[3] = (short)f2b(xo.w);
  *(s16x4*)(x + (size_t)bt * 1024 + e) = xb;
  uint32_t pk = (uint32_t)f8(xo.x * lv.x * 0.1f * sh)
              | ((uint32_t)f8(xo.y * lv.y * 0.1f * sh) << 8)
              | ((uint32_t)f8(xo.z * lv.z * 0.1f * sh) << 16)
              | ((uint32_t)f8(xo.w * lv.w * 0.1f * sh) << 24);
  *(uint32_t*)(h8 + (size_t)bt * 1024 + ipos(e)) = pk;
}

// transpose+convert f32 -> fp8 I64
__global__ __launch_bounds__(256) void cvtT8_k(const float* __restrict__ src, uint8_t* __restrict__ dst,
                                               float scale) {
  __shared__ float tl[64][68];
  const int z = blockIdx.z;
  const int c0 = blockIdx.x * 64, r0 = blockIdx.y * 64;
  const int tid = threadIdx.x;
  const float* s = src + (size_t)z * 1048576;
#pragma unroll
  for (int it = 0; it < 4; ++it) {
    const int r = it * 16 + (tid >> 4);
    const int c4 = (tid & 15) * 4;
    const float4 v = *(const float4*)(s + (size_t)(r0 + r) * 1024 + c0 + c4);
    tl[r][c4] = v.x; tl[r][c4 + 1] = v.y; tl[r][c4 + 2] = v.z; tl[r][c4 + 3] = v.w;
  }
  __syncthreads();
  const int c = tid >> 2;
  const int rr = (tid & 3) * 16;
  const int base = r0 + rr;
  const int O = (base & ~63) | ((base & 32) >> 2) | ((base & 16) << 1);
  uint8_t* d = dst + (size_t)z * 1048576 + (size_t)(c0 + c) * 1024 + O;
  uint32_t w0 = 0, w1 = 0, w2 = 0, w3 = 0;
#pragma unroll
  for (int j = 0; j < 4; ++j) w0 |= (uint32_t)f8(tl[rr + j][c] * scale) << (8 * j);
#pragma unroll
  for (int j = 0; j < 4; ++j) w1 |= (uint32_t)f8(tl[rr + 4 + j][c] * scale) << (8 * j);
#pragma unroll
  for (int j = 0; j < 4; ++j) w2 |= (uint32_t)f8(tl[rr + 8 + j][c] * scale) << (8 * j);
#pragma unroll
  for (int j = 0; j < 4; ++j) w3 |= (uint32_t)f8(tl[rr + 12 + j][c] * scale) << (8 * j);
  *(uint32_t*)d = w0;        *(uint32_t*)(d + 4) = w1;
  *(uint32_t*)(d + 16) = w2; *(uint32_t*)(d + 20) = w3;
}

// f32 -> fp8 (scaled, I64-interleaved)
__global__ __launch_bounds__(256) void cvtf8i_k(const float* __restrict__ src, uint8_t* __restrict__ dst,
                                                long long n, float scale) {
  long long i = ((long long)blockIdx.x * 256 + threadIdx.x) * 8;
  const long long stride = (long long)gridDim.x * 256 * 8;
  for (; i < n; i += stride) {
    const float4 a = *(const float4*)(src + i);
    const float4 b = *(const float4*)(src + i + 4);
    uint32_t lo = (uint32_t)f8(a.x * scale) | ((uint32_t)f8(a.y * scale) << 8)
                | ((uint32_t)f8(a.z * scale) << 16) | ((uint32_t)f8(a.w * scale) << 24);
    uint32_t hi = (uint32_t)f8(b.x * scale) | ((uint32_t)f8(b.y * scale) << 8)
                | ((uint32_t)f8(b.z * scale) << 16) | ((uint32_t)f8(b.w * scale) << 24);
    uint8_t* d = dst + ((i & ~63ll) | (((i >> 3) & 3) << 4) | (((i >> 5) & 1) << 3));
    *(uint32_t*)d = lo;
    *(uint32_t*)(d + 4) = hi;
  }
}

// all-layers f32 -> fp8 (scaled, I64): per layer [wq 1M][wk 1M][f1 2M][f2 2M]
__global__ __launch_bounds__(256) void megacvt8_k(const float* __restrict__ wq, const float* __restrict__ wk,
                                                  const float* __restrict__ f1, const float* __restrict__ f2,
                                                  uint8_t* __restrict__ dst, float scale) {
  const long long M1 = 1ll << 20;
  const long long per = 6 * M1;
  const long long total = 12 * per;
  long long i = ((long long)blockIdx.x * 256 + threadIdx.x) * 8;
  const long long stride = (long long)gridDim.x * 256 * 8;
  for (; i < total; i += stride) {
    const long long l = i / per;
    const long long off = i - l * per;
    const float* s; long long so;
    if      (off < M1)     { s = wq; so = l * M1 + off; }
    else if (off < 2 * M1) { s = wk; so = l * M1 + off - M1; }
    else if (off < 4 * M1) { s = f1; so = l * 2 * M1 + off - 2 * M1; }
    else                   { s = f2; so = l * 2 * M1 + off - 4 * M1; }
    const float4 a = *(const float4*)(s + so);
    const float4 b = *(const float4*)(s + so + 4);
    uint32_t lo = (uint32_t)f8(a.x * scale) | ((uint32_t)f8(a.y * scale) << 8)
                | ((uint32_t)f8(a.z * scale) << 16) | ((uint32_t)f8(a.w * scale) << 24);
    uint32_t hi = (uint32_t)f8(b.x * scale) | ((uint32_t)f8(b.y * scale) << 8)
                | ((uint32_t)f8(b.z * scale) << 16) | ((uint32_t)f8(b.w * scale) << 24);
    uint8_t* d = dst + ((i & ~63ll) | (((i >> 3) & 3) << 4) | (((i >> 5) & 1) << 3));
    *(uint32_t*)d = lo;
    *(uint32_t*)(d + 4) = hi;
  }
}

// --------------------------------------------------------------- host side --
static inline double scp(double sigma) {
  double e = round(log2(0.5 / sigma));
  if (e > 120.0) e = 120.0;
  if (e < -120.0) e = -120.0;
  return ldexp(1.0, (int)e);
}
static inline void split2(double v, float& a, float& b) {
  if (v == 0.0) { a = 0.f; b = 0.f; return; }
  int e; frexp(v, &e);
  int h = e / 2;
  a = (float)ldexp(1.0, h);
  b = (float)ldexp(v, -h);
}

extern "C" void kernel_launch(void* const* d_in, const int* in_sizes, int n_in,
                              void* d_out, int out_size, void* d_ws, size_t ws_size,
                              hipStream_t stream) {
  const int*   idx  = (const int*)  d_in[0];
  const float* wte  = (const float*)d_in[1];
  const float* wpe  = (const float*)d_in[2];
  const float* ln1w = (const float*)d_in[3];
  const float* Wq   = (const float*)d_in[4];
  const float* Wk   = (const float*)d_in[5];
  const float* Wv   = (const float*)d_in[6];
  const float* Wo   = (const float*)d_in[7];
  const float* ln2w = (const float*)d_in[8];
  const float* fc1  = (const float*)d_in[9];
  const float* fc2  = (const float*)d_in[10];
  const float* lnfw = (const float*)d_in[11];
  const float* lmh  = (const float*)d_in[12];
  float* out = (float*)d_out;

  // per-layer power-of-2 scale frames
  double dSh1[12], dSqk[12], dSaq[12], dSu[12], dSh2[12], dSmq[12], dShF;
  {
    double sx = 7e-5;
    for (int l = 0; l < 12; ++l) {
      double sh1 = sx * 0.1;
      double sq  = sh1 * 0.005 * 32.0 * 0.01;
      double saq = 32.0 * sq * sq * 0.01 * 0.1;
      double su  = sh1 * 8e-4 * 32.0 * 0.1;
      double sx2 = sx * 0.05;
      double sh2 = sx2 * 0.1;
      double smq = sh2 * 0.005 * 32.0 * 0.05 * 0.1;
      dSh1[l] = scp(sh1); dSqk[l] = scp(sq); dSaq[l] = scp(saq);
      dSu[l] = scp(su); dSh2[l] = scp(sh2); dSmq[l] = scp(smq);
      sx = sx2 * 0.05 * (l < 11 ? 0.1 : 1.0);
    }
    dShF = scp(sx * 0.1);
  }
  const double SW = 128.0, SWVO = 512.0, SF = 128.0, SL = 128.0;

  // workspace (~124MB)
  char* w = (char*)d_ws;
  u16*     x    = (u16*)w;      w += (size_t)4096 * 1024 * 2;   // 8MB (bf16 residual)
  uint8_t* h8   = (uint8_t*)w;  w += (size_t)4096 * 1024;       // 4MB
  uint8_t* q8   = (uint8_t*)w;  w += (size_t)4096 * 1024;       // 4MB
  uint8_t* k8   = (uint8_t*)w;  w += (size_t)4096 * 1024;       // 4MB
  uint8_t* uT8  = (uint8_t*)w;  w += (size_t)2 * 1024 * 2048;   // 4MB
  uint8_t* a8   = (uint8_t*)w;  w += (size_t)2 * 2048 * 2048;   // 8MB
  uint8_t* mb8  = (uint8_t*)w;  w += (size_t)4096 * 2048;       // 8MB
  uint8_t* lw8  = (uint8_t*)w;  w += (size_t)12 * 6291456;      // 72MB
  uint8_t* wvo8 = (uint8_t*)w;  w += (size_t)12 * 1048576;      // 12MB
  uint8_t* lmh8 = q8;                       // 32MB alias (q8..mb8 + lw8 head), dead at lm_head
  uint8_t* wvT8 = lw8;                      // pre-phase aliases inside lw8
  uint8_t* wo8  = lw8 + 25165824;

  const size_t SHP = 73728, SHT = 49152, SHH = 73728;

  embed8_k<<<4096, 256, 0, stream>>>(idx, wte, wpe, ln1w, x, h8, (float)dSh1[0]);

  // Wvo[l] = Wo[l] @ Wv[l], all-fp8
  cvtT8_k<<<dim3(16, 16, 12), 256, 0, stream>>>(Wv, wvT8, (float)SW);
  cvtf8i_k<<<2048, 256, 0, stream>>>(Wo, wo8, 12ll * 1048576, (float)SW);
  {
    GP8 p{};
    p.A = wo8; p.asb = 1048576;
    p.B[0] = wvT8; p.bsb = 1048576;
    p.O[0] = wvo8; p.osb = 1048576;
    p.K = 1024; p.lda = 1024; p.ldb = 1024; p.ldo = 1024;
    split2(SWVO / (SW * SW), p.m1[0], p.m2[0]);
    p.epi[0] = 0;
    gemm8t_k<<<dim3(8, 8, 12), 256, SHT, stream>>>(p);
  }
  megacvt8_k<<<2048, 256, 0, stream>>>(Wq, Wk, fc1, fc2, lw8, (float)SW);

  for (int l = 0; l < 12; ++l) {
    uint8_t* lwl = lw8 + (size_t)l * 6291456;
    { // QKU fused N=3072 (gemm8p, 384 blocks all-resident, 83% cap). K=1024
      GP8 p{};
      p.A = h8; p.asb = 0;
      p.B[0] = lwl; p.B[1] = lwl + 1048576; p.B[2] = wvo8 + (size_t)l * 1048576; p.bsb = 0;
      p.O[0] = q8; p.O[1] = k8; p.O[2] = uT8; p.osb = 0;
      p.K = 1024; p.lda = 1024; p.ldb = 1024; p.ldo = 1024;
      split2(0.01 * dSqk[l] / (dSh1[l] * SW), p.m1[0], p.m2[0]);
      p.m1[1] = p.m1[0]; p.m2[1] = p.m2[0];
      split2(0.1 * dSu[l] / (dSh1[l] * SWVO), p.m1[2], p.m2[2]);
      p.epi[0] = 0; p.epi[1] = 0; p.epi[2] = 1;
      p.nsel = 1;
      gemm8p_k<<<dim3(24, 16, 1), 256, SHP, stream>>>(p);
    }
    { // a = quad(q @ k^T * 0.01) per batch (gemm8t, 512 blocks, 3 blk/CU). K=1024
      GP8 p{};
      p.A = q8; p.asb = 2097152;
      p.B[0] = k8; p.bsb = 2097152;
      p.O[0] = a8; p.osb = 4194304;
      p.K = 1024; p.lda = 1024; p.ldb = 1024; p.ldo = 2048;
      split2(0.001 * dSaq[l] / (dSqk[l] * dSqk[l]), p.m1[0], p.m2[0]);
      p.qc = (float)(10.0 / dSaq[l]);
      p.epi[0] = 2;
      gemm8t_k<<<dim3(16, 16, 2), 256, SHT, stream>>>(p);
    }
    { // x = (x + (a@u)*0.001)*0.05 ; h8 = x*ln2*0.1 (gemm8h, 512 blocks). K=2048
      GP8 p{};
      p.A = a8; p.asb = 0;
      p.B[0] = uT8; p.bsb = 2097152; p.msel = 1;
      p.O[0] = a8; p.osb = 0;
      p.K = 2048; p.lda = 2048; p.ldb = 2048; p.ldo = 1024;
      split2(0.001 / (dSaq[l] * dSu[l]), p.m1[0], p.m2[0]);
      p.epi[0] = 3;
      p.xres = x; p.lnw = ln2w + (size_t)l * 1024; p.rscale = 0.05f;
      p.oscale = (float)dSh2[l]; p.h8out = h8;
      gemm8h_k<<<dim3(64, 8, 1), 256, SHH, stream>>>(p);
    }
    { // m = quad(h @ fc1^T * 0.05) (gemm8t, 512 blocks). K=1024, N=2048
      GP8 p{};
      p.A = h8; p.asb = 0;
      p.B[0] = lwl + 2097152; p.bsb = 0;
      p.O[0] = mb8; p.osb = 0;
      p.K = 1024; p.lda = 1024; p.ldb = 1024; p.ldo = 2048;
      split2(0.005 * dSmq[l] / (dSh2[l] * SF), p.m1[0], p.m2[0]);
      p.qc = (float)(10.0 / dSmq[l]);
      p.epi[0] = 2;
      gemm8t_k<<<dim3(32, 16, 1), 256, SHT, stream>>>(p);
    }
    { // x = (x + m@fc2^T*0.05)*0.05*s ; h8_next (gemm8h, 512 blocks). K=2048
      GP8 p{};
      p.A = mb8; p.asb = 0;
      p.B[0] = lwl + 4194304; p.bsb = 0;
      p.O[0] = mb8; p.osb = 0;
      p.K = 2048; p.lda = 2048; p.ldb = 2048; p.ldo = 1024;
      split2(0.05 / (dSmq[l] * SF), p.m1[0], p.m2[0]);
      p.epi[0] = 3;
      p.xres = x;
      p.rscale = (l < 11) ? 0.005f : 0.05f;
      if (l < 11) { p.lnw = ln1w + (size_t)(l + 1) * 1024; p.oscale = (float)dSh1[l + 1]; }
      else        { p.lnw = lnfw; p.oscale = (float)dShF; }
      p.h8out = h8;
      gemm8h_k<<<dim3(64, 8, 1), 256, SHH, stream>>>(p);
    }
  }

  // lm_head in fp8 (gemm8p, 4000 blocks, f32 NT out)
  cvtf8i_k<<<2048, 256, 0, stream>>>(lmh, lmh8, 32768000ll, (float)SL);
  {
    GP8 p{};
    p.A = h8; p.asb = 0;
    p.B[0] = lmh8; p.bsb = 0;
    p.O[0] = lmh8; p.osb = 0;
    p.K = 1024; p.lda = 1024; p.ldb = 1024; p.ldo = 0;
    split2(0.5 / (dShF * SL), p.m1[0], p.m2[0]);
    p.epi[0] = 4;
    p.fout = out; p.ldf = 32000;
    gemm8p_k<<<dim3(250, 16, 1), 256, SHP, stream>>>(p);
  }
}